// Round 11
// baseline (140.303 us; speedup 1.0000x reference)
//
#include <hip/hip_runtime.h>

// HolonomyAttention: out = softmax_causal((Q @ C_h) K^T / sqrt(D)) V
// B=2 H=16 T=2048 D=64, fp32 in/out.
// Round 20: synthesis of the two proven-good pieces that were never
// combined: (a) 32-row waves sharing K/V operands across 2 strips (halves
// LDS-read bytes/tile; body measured VGPR 68, r15/r16), (b) LDS dbuf
// staging + full-depth (bh,qi) blocks + LPT mapping + 4 blocks/CU
// (r14/r19 packing). Block = 64-row tile, 4 waves = (hv, par): each wave
// 32 rows, computes tiles of its j-parity; all waves co-issue DMA and
// barrier every tile. Epilogue parity-combine reuses the (dead) staging
// ring as scratch so LDS stays 32KB -> 4 blocks/CU.
// prep kernels unchanged (plane-split frag layout).

typedef __attribute__((ext_vector_type(8))) short short8;           // 8 bf16
typedef __attribute__((ext_vector_type(8))) unsigned short ushort8;
typedef __attribute__((ext_vector_type(4))) float f32x4;
typedef __attribute__((ext_vector_type(2))) _Float16 half2v;
typedef __attribute__((ext_vector_type(4))) _Float16 half4;
typedef __attribute__((ext_vector_type(8))) _Float16 half8;

constexpr int Tc = 2048;
constexpr int Dc = 64;
constexpr size_t REGION = (size_t)32 * Tc * Dc;   // 4,194,304 elems = 8 MiB u16

__device__ inline unsigned short f2bf(float f) {   // fp32 -> bf16 RNE
    union { float f; unsigned u; } x; x.f = f;
    return (unsigned short)((x.u + 0x7fffu + ((x.u >> 16) & 1u)) >> 16);
}

__device__ inline half2v pkrtz(float a, float b) {
    return __builtin_bit_cast(half2v, __builtin_amdgcn_cvt_pkrtz(a, b));
}

#define MFMA_BF16_K32(a, b, c) __builtin_amdgcn_mfma_f32_16x16x32_bf16((a), (b), (c), 0, 0, 0)
#define MFMA_F16_K16(a, b, c)  __builtin_amdgcn_mfma_f32_16x16x16f16((a), (b), (c), 0, 0, 0)

// async global->LDS copy: per-lane global addr, wave-uniform LDS base,
// HW deposits at base + lane*16.
typedef __attribute__((address_space(3))) unsigned int        lds_u32;
typedef const __attribute__((address_space(1))) unsigned int  glob_u32;
__device__ __attribute__((always_inline)) inline void gl_lds16(const void* g, void* l) {
    __builtin_amdgcn_global_load_lds((glob_u32*)g, (lds_u32*)l, 16, 0, 0);
}

// ---------------------------------------------------------------------------
// Kernel 0: C^T B-operand fragments per head (tiny, one-time).
// ---------------------------------------------------------------------------
__global__ __launch_bounds__(256, 1)
void holo_cfrag(const float* __restrict__ Cp, unsigned short* __restrict__ cfrag_g)
{
    const int t = threadIdx.x, lane = t & 63, eb = t >> 6;
    const int l15 = lane & 15, quad = lane >> 4;
    const int h = blockIdx.x;
    const float* Cg = Cp + (size_t)h * Dc * Dc;
    #pragma unroll
    for (int half = 0; half < 2; ++half) {
        short8 b;
        #pragma unroll
        for (int jj = 0; jj < 8; ++jj) {
            const int d = half * 32 + quad * 8 + jj;
            b[jj] = (short)f2bf(Cg[d * Dc + eb * 16 + l15]);
        }
        *(short8*)(&cfrag_g[(((size_t)h * 4 + eb) * 2 + half) * 512 + lane * 8]) = b;
    }
}

// ---------------------------------------------------------------------------
// Kernel 1: prepass, one block per (bh, 64-row tile st). LDS-staged.
// K/V fragment tiles PLANE-SPLIT within each 8KB tile:
//   ktile[0..2047]    = kf0 chunks, (tn*64+lane)*8 u16   (16B per lane)
//   ktile[2048..4095] = kf1 chunks
//   vtile likewise (v0 plane | v1 plane, f16)
// ---------------------------------------------------------------------------
__global__ __launch_bounds__(256, 4)
void holo_prep8(const float* __restrict__ Qp, const float* __restrict__ Kp,
                const float* __restrict__ Vp,
                const unsigned short* __restrict__ cfrag_g,
                unsigned short* __restrict__ qfrag_g,
                unsigned short* __restrict__ kfrag_g,
                _Float16* __restrict__ vfrag_g)
{
    __shared__ unsigned short kt[64 * 72];   // K tile bf16 natural [s][d]
    __shared__ unsigned short qt[64 * 72];   // Q tile bf16 natural [r][d]
    __shared__ _Float16      vt[64 * 72];    // V tile f16 natural [s][d]
    __shared__ unsigned short pf[64 * 72];   // Qrot C->B-frag round trip

    const int t = threadIdx.x, lane = t & 63, w = t >> 6;
    const int l15 = lane & 15, quad = lane >> 4, wb = w * 16;
    const int n = blockIdx.x, bh = n >> 5, st = n & 31, h = bh & 15;
    const int s0 = st * 64;

    const float* Qg = Qp + ((size_t)bh * Tc + s0) * Dc;
    const float* Kg = Kp + ((size_t)bh * Tc + s0) * Dc;
    const float* Vg = Vp + ((size_t)bh * Tc + s0) * Dc;

    // ---- stage all three tiles (coalesced float4 reads, cvt, LDS write) ----
    #pragma unroll
    for (int kk = 0; kk < 4; ++kk) {
        const int flat = kk * 1024 + t * 4;
        const int r = flat >> 6, d0 = flat & 63;
        float4 kv = *(const float4*)(&Kg[flat]);
        ushort4 kp; kp.x = f2bf(kv.x); kp.y = f2bf(kv.y); kp.z = f2bf(kv.z); kp.w = f2bf(kv.w);
        *(ushort4*)(&kt[r * 72 + d0]) = kp;
        float4 qv = *(const float4*)(&Qg[flat]);
        ushort4 qp; qp.x = f2bf(qv.x); qp.y = f2bf(qv.y); qp.z = f2bf(qv.z); qp.w = f2bf(qv.w);
        *(ushort4*)(&qt[r * 72 + d0]) = qp;
        float4 vv = *(const float4*)(&Vg[flat]);
        half4 vp;
        vp[0] = (_Float16)vv.x; vp[1] = (_Float16)vv.y;
        vp[2] = (_Float16)vv.z; vp[3] = (_Float16)vv.w;
        *(half4*)(&vt[r * 72 + d0]) = vp;
    }
    __syncthreads();

    // ---- K fragments (wave w handles tn = w): plane-split writes ----
    {
        const int row = wb + l15;
        ushort8 p0 = *(const ushort8*)(&kt[row * 72 + quad * 8]);
        ushort8 p1 = *(const ushort8*)(&kt[row * 72 + 32 + quad * 8]);
        unsigned short* ktile = kfrag_g + (size_t)(bh * 32 + st) * 4096;
        *(ushort8*)(&ktile[(w * 64 + lane) * 8])        = p0;
        *(ushort8*)(&ktile[2048 + (w * 64 + lane) * 8]) = p1;
    }

    // ---- V fragments: plane-split writes ----
    {
        half8 v0, v1;
        #pragma unroll
        for (int dn = 0; dn < 2; ++dn)
            #pragma unroll
            for (int i = 0; i < 4; ++i)
                v0[dn * 4 + i] = vt[(wb + quad * 4 + i) * 72 + dn * 16 + l15];
        #pragma unroll
        for (int dn = 0; dn < 2; ++dn)
            #pragma unroll
            for (int i = 0; i < 4; ++i)
                v1[dn * 4 + i] = vt[(wb + quad * 4 + i) * 72 + (dn + 2) * 16 + l15];
        _Float16* vtile = vfrag_g + (size_t)(bh * 32 + st) * 4096;
        *(half8*)(&vtile[(w * 64 + lane) * 8])        = v0;
        *(half8*)(&vtile[2048 + (w * 64 + lane) * 8]) = v1;
    }

    // ---- Qrot strip (rows s0+wb..+15): A from qt LDS, B from cfrag ----
    {
        short8 a0 = *(const short8*)(&qt[(wb + l15) * 72 + quad * 8]);
        short8 a1 = *(const short8*)(&qt[(wb + l15) * 72 + 32 + quad * 8]);
        #pragma unroll
        for (int eb = 0; eb < 4; ++eb) {
            short8 b0 = *(const short8*)(&cfrag_g[(((size_t)h * 4 + eb) * 2 + 0) * 512 + lane * 8]);
            short8 b1 = *(const short8*)(&cfrag_g[(((size_t)h * 4 + eb) * 2 + 1) * 512 + lane * 8]);
            f32x4 c = {0.f, 0.f, 0.f, 0.f};
            c = MFMA_BF16_K32(a0, b0, c);
            c = MFMA_BF16_K32(a1, b1, c);
            #pragma unroll
            for (int i = 0; i < 4; ++i)   // fold 0.125 * log2(e)
                pf[(wb + quad * 4 + i) * 72 + eb * 16 + l15] = f2bf(c[i] * 0.18033688f);
        }
        __threadfence_block();   // wave-local rows: order writes before reads
        short8 fa0 = *(const short8*)(&pf[(wb + l15) * 72 + quad * 8]);
        short8 fa1 = *(const short8*)(&pf[(wb + l15) * 72 + 32 + quad * 8]);
        const size_t strip = (size_t)bh * 128 + st * 4 + w;
        *(short8*)(&qfrag_g[strip * 1024 + lane * 8]) = fa0;
        *(short8*)(&qfrag_g[strip * 1024 + 512 + lane * 8]) = fa1;
    }
}

// ---------------------------------------------------------------------------
// Kernel 2: attention. 1 block = 1 (bh,qi) 64-row tile. 4 waves = (hv,par):
// wave owns 32 rows (2 strips), computes tiles with (j&1)==par. All waves
// co-issue the next tile's DMA + hit every per-tile barrier (wave-uniform).
// K/V regs shared across both strips -> 32 b128 LDS reads/tile (half of
// r19). Epilogue parity-combine aliases the dead staging ring. LPT map.
// ---------------------------------------------------------------------------
__global__ __launch_bounds__(256, 4)
void holo_attn20(const unsigned short* __restrict__ qfrag_g,
                 const unsigned short* __restrict__ kfrag_g,
                 const _Float16* __restrict__ vfrag_g,
                 float* __restrict__ Op)
{
    __shared__ __align__(16) unsigned char smem[32768];
    unsigned short (*bufK)[4096] = (unsigned short (*)[4096])smem;          // 2 x 8KB
    _Float16       (*bufV)[4096] = (_Float16 (*)[4096])(smem + 16384);      // 2 x 8KB
    // epilogue aliases (used only after the loop's final barrier):
    float* lds_o = (float*)smem;                 // [hv][s2][16][68] = 17408 B
    float* lds_l = (float*)(smem + 24576);       // [hv][s2][16]     = 256 B

    const int t = threadIdx.x, lane = t & 63, wid = t >> 6;
    const int l15 = lane & 15, quad = lane >> 4;
    const int hv  = wid & 1;      // row half: strips 2*hv, 2*hv+1
    const int par = wid >> 1;     // j parity

    // LPT + XCD-affine mapping: qi descends with dispatch order.
    const int id = blockIdx.x;
    const int xcd = id & 7, sseq = id >> 3;          // 128 blocks per XCD
    const int qi = 31 - (sseq >> 2);
    const int bh = xcd * 4 + (sseq & 3);
    const int q0 = qi * 64;

    const char* kbase = (const char*)(kfrag_g + (size_t)bh * 32 * 4096);
    const char* vbase = (const char*)(vfrag_g + (size_t)bh * 32 * 4096);

    // ---- stage tile 0 into ring slot 0 (4 loads per wave) ----
    gl_lds16(kbase + wid * 1024 + lane * 16,        &bufK[0][wid * 512]);
    gl_lds16(kbase + 4096 + wid * 1024 + lane * 16, &bufK[0][2048 + wid * 512]);
    gl_lds16(vbase + wid * 1024 + lane * 16,        &bufV[0][wid * 512]);
    gl_lds16(vbase + 4096 + wid * 1024 + lane * 16, &bufV[0][2048 + wid * 512]);

    // Qrot B-fragments for this wave's two strips (scale*log2e folded in)
    short8 qa0[2], qa1[2];
    #pragma unroll
    for (int s2 = 0; s2 < 2; ++s2) {
        const size_t strip = (size_t)bh * 128 + qi * 4 + (2 * hv + s2);
        qa0[s2] = *(const short8*)(&qfrag_g[strip * 1024 + lane * 8]);
        qa1[s2] = *(const short8*)(&qfrag_g[strip * 1024 + 512 + lane * 8]);
    }

    f32x4 o[2][4];                // o[s2][dn][i]: O[q=l15][d=dn*16+quad*4+i]
    #pragma unroll
    for (int s2 = 0; s2 < 2; ++s2)
        #pragma unroll
        for (int dn = 0; dn < 4; ++dn) o[s2][dn] = f32x4{0.f, 0.f, 0.f, 0.f};
    float l2[2] = {0.f, 0.f};

    const int rowgA = q0 + (2 * hv) * 16 + l15;   // strip 2hv global q row
    const int rowgB = rowgA + 16;                 // strip 2hv+1

    asm volatile("s_waitcnt vmcnt(0)" ::: "memory");
    __builtin_amdgcn_sched_barrier(0);
    __syncthreads();

    int cur = 0;
    for (int j = 0; j <= qi; ++j) {
        // ---- all waves co-issue next tile's DMA into the other slot ----
        if (j < qi) {
            const char* ks = kbase + (size_t)(j + 1) * 8192;
            const char* vs = vbase + (size_t)(j + 1) * 8192;
            const int nb = cur ^ 1;
            gl_lds16(ks + wid * 1024 + lane * 16,        &bufK[nb][wid * 512]);
            gl_lds16(ks + 4096 + wid * 1024 + lane * 16, &bufK[nb][2048 + wid * 512]);
            gl_lds16(vs + wid * 1024 + lane * 16,        &bufV[nb][wid * 512]);
            gl_lds16(vs + 4096 + wid * 1024 + lane * 16, &bufV[nb][2048 + wid * 512]);
        }

        // ---- only the parity-matched waves compute this tile ----
        if ((j & 1) == par) {
            const unsigned short* Kl = &bufK[cur][0];
            const _Float16*       Vl = &bufV[cur][0];

            // ---- S^T = K * Qrot^T, both strips share K regs ----
            f32x4 stA[4], stB[4];
            __builtin_amdgcn_s_setprio(1);
            #pragma unroll
            for (int tn = 0; tn < 4; ++tn) {
                short8 k0 = *(const short8*)(&Kl[(tn * 64 + lane) * 8]);
                short8 k1 = *(const short8*)(&Kl[2048 + (tn * 64 + lane) * 8]);
                f32x4 cA = {0.f, 0.f, 0.f, 0.f};
                cA = MFMA_BF16_K32(k0, qa0[0], cA);
                cA = MFMA_BF16_K32(k1, qa1[0], cA);
                stA[tn] = cA;
                f32x4 cB = {0.f, 0.f, 0.f, 0.f};
                cB = MFMA_BF16_K32(k0, qa0[1], cB);
                cB = MFMA_BF16_K32(k1, qa1[1], cB);
                stB[tn] = cB;
            }
            __builtin_amdgcn_s_setprio(0);

            // ---- mask + fixed-shift softmax; packed f16 cvt ----
            half4 paA[4], paB[4];
            #pragma unroll
            for (int tn = 0; tn < 4; ++tn) {
                float pA[4], pB[4];
                #pragma unroll
                for (int i = 0; i < 4; ++i) {
                    float svA = stA[tn][i], svB = stB[tn][i];
                    if (j == qi) {
                        const int colg = j * 64 + tn * 16 + quad * 4 + i;
                        if (colg > rowgA) svA = -1e30f;
                        if (colg > rowgB) svB = -1e30f;
                    }
                    pA[i] = __builtin_amdgcn_exp2f(svA);
                    pB[i] = __builtin_amdgcn_exp2f(svB);
                    l2[0] += pA[i];
                    l2[1] += pB[i];
                }
                half2v loA = pkrtz(pA[0], pA[1]), hiA = pkrtz(pA[2], pA[3]);
                paA[tn] = __builtin_shufflevector(loA, hiA, 0, 1, 2, 3);
                half2v loB = pkrtz(pB[0], pB[1]), hiB = pkrtz(pB[2], pB[3]);
                paB[tn] = __builtin_shufflevector(loB, hiB, 0, 1, 2, 3);
            }

            // ---- O^T += V^T * P, both strips share V regs ----
            __builtin_amdgcn_s_setprio(1);
            #pragma unroll
            for (int tn = 0; tn < 4; ++tn) {
                half8 vl = *(const half8*)(&Vl[(tn * 64 + lane) * 8]);
                half8 vh = *(const half8*)(&Vl[2048 + (tn * 64 + lane) * 8]);
                half4 vf0 = __builtin_shufflevector(vl, vl, 0, 1, 2, 3);
                half4 vf1 = __builtin_shufflevector(vl, vl, 4, 5, 6, 7);
                half4 vf2 = __builtin_shufflevector(vh, vh, 0, 1, 2, 3);
                half4 vf3 = __builtin_shufflevector(vh, vh, 4, 5, 6, 7);
                o[0][0] = MFMA_F16_K16(vf0, paA[tn], o[0][0]);
                o[0][1] = MFMA_F16_K16(vf1, paA[tn], o[0][1]);
                o[0][2] = MFMA_F16_K16(vf2, paA[tn], o[0][2]);
                o[0][3] = MFMA_F16_K16(vf3, paA[tn], o[0][3]);
                o[1][0] = MFMA_F16_K16(vf0, paB[tn], o[1][0]);
                o[1][1] = MFMA_F16_K16(vf1, paB[tn], o[1][1]);
                o[1][2] = MFMA_F16_K16(vf2, paB[tn], o[1][2]);
                o[1][3] = MFMA_F16_K16(vf3, paB[tn], o[1][3]);
            }
            __builtin_amdgcn_s_setprio(0);
        }

        // ---- flip: next DMA landed + all waves done reading cur ----
        asm volatile("s_waitcnt vmcnt(0)" ::: "memory");
        __builtin_amdgcn_sched_barrier(0);
        __syncthreads();
        cur ^= 1;
    }

    // ---- per-strip row sums (quad partials -> full row sum) ----
    #pragma unroll
    for (int s2 = 0; s2 < 2; ++s2) {
        l2[s2] += __shfl_xor(l2[s2], 16);
        l2[s2] += __shfl_xor(l2[s2], 32);
    }

    // ---- parity-combine epilogue in the (dead) staging ring ----
    // layout: lds_o[((hv*2+s2)*16 + row)*68 + d], lds_l[(hv*2+s2)*16 + row]
    if (par == 1) {
        #pragma unroll
        for (int s2 = 0; s2 < 2; ++s2) {
            float* po = lds_o + (size_t)((hv * 2 + s2) * 16 + l15) * 68;
            #pragma unroll
            for (int dn = 0; dn < 4; ++dn) {
                float4 r;
                r.x = o[s2][dn][0]; r.y = o[s2][dn][1];
                r.z = o[s2][dn][2]; r.w = o[s2][dn][3];
                *(float4*)(&po[dn * 16 + quad * 4]) = r;
            }
            if (quad == 0) lds_l[(hv * 2 + s2) * 16 + l15] = l2[s2];
        }
    }
    __syncthreads();
    if (par == 0) {
        #pragma unroll
        for (int s2 = 0; s2 < 2; ++s2) {
            const float inv = 1.0f / (l2[s2] + lds_l[(hv * 2 + s2) * 16 + l15]);
            const int rowg = q0 + (2 * hv + s2) * 16 + l15;
            float* dst = Op + ((size_t)bh * Tc + rowg) * Dc;
            const float* po = lds_o + (size_t)((hv * 2 + s2) * 16 + l15) * 68;
            #pragma unroll
            for (int dn = 0; dn < 4; ++dn) {
                float4 r;
                r.x = (o[s2][dn][0] + po[dn * 16 + quad * 4 + 0]) * inv;
                r.y = (o[s2][dn][1] + po[dn * 16 + quad * 4 + 1]) * inv;
                r.z = (o[s2][dn][2] + po[dn * 16 + quad * 4 + 2]) * inv;
                r.w = (o[s2][dn][3] + po[dn * 16 + quad * 4 + 3]) * inv;
                *(float4*)(&dst[dn * 16 + quad * 4]) = r;
            }
        }
    }
}

extern "C" void kernel_launch(void* const* d_in, const int* in_sizes, int n_in,
                              void* d_out, int out_size, void* d_ws, size_t ws_size,
                              hipStream_t stream) {
    const float* Q = (const float*)d_in[0];
    const float* K = (const float*)d_in[1];
    const float* V = (const float*)d_in[2];
    // d_in[3] = causal mask (analytic — unused)
    const float* C = (const float*)d_in[4];
    float* O = (float*)d_out;

    unsigned short* qfrag_w = (unsigned short*)d_ws;              // 8 MiB
    unsigned short* kfrag_w = qfrag_w + REGION;                   // 8 MiB
    _Float16*       vfrag_w = (_Float16*)(kfrag_w + REGION);      // 8 MiB
    unsigned short* cfrag_w = (unsigned short*)(vfrag_w + REGION);// 128 KiB

    holo_cfrag<<<dim3(16), dim3(256), 0, stream>>>(C, cfrag_w);
    holo_prep8<<<dim3(1024), dim3(256), 0, stream>>>(Q, K, V, cfrag_w, qfrag_w, kfrag_w, vfrag_w);
    holo_attn20<<<dim3(1024), dim3(256), 0, stream>>>(qfrag_w, kfrag_w, vfrag_w, O);
}

// Round 12
// 136.173 us; speedup vs baseline: 1.0303x; 1.0303x over previous
//
#include <hip/hip_runtime.h>

// HolonomyAttention: out = softmax_causal((Q @ C_h) K^T / sqrt(D)) V
// B=2 H=16 T=2048 D=64, fp32 in/out.
// Round 21 = r19 frame + T4 counted-vmcnt 3-deep DMA ring. All prior
// variants were single-tile-deep pipelines (vmcnt(0) drain or implicit
// 1-tile reg prefetch): next tile's L2->LDS round trip covered only by
// ~400cyc of compute. Here 2 tiles stay in flight across raw s_barriers
// (vmcnt(8)/4/0 tail), drain-0 never in steady state. LDS 48KB -> 3
// blocks/CU, bounds(256,3); body is the proven VGPR-68 JIT-ds_read loop.
// prep kernels unchanged (plane-split frag layout).

typedef __attribute__((ext_vector_type(8))) short short8;           // 8 bf16
typedef __attribute__((ext_vector_type(8))) unsigned short ushort8;
typedef __attribute__((ext_vector_type(4))) float f32x4;
typedef __attribute__((ext_vector_type(2))) _Float16 half2v;
typedef __attribute__((ext_vector_type(4))) _Float16 half4;
typedef __attribute__((ext_vector_type(8))) _Float16 half8;

constexpr int Tc = 2048;
constexpr int Dc = 64;
constexpr size_t REGION = (size_t)32 * Tc * Dc;   // 4,194,304 elems = 8 MiB u16

__device__ inline unsigned short f2bf(float f) {   // fp32 -> bf16 RNE
    union { float f; unsigned u; } x; x.f = f;
    return (unsigned short)((x.u + 0x7fffu + ((x.u >> 16) & 1u)) >> 16);
}

__device__ inline half2v pkrtz(float a, float b) {
    return __builtin_bit_cast(half2v, __builtin_amdgcn_cvt_pkrtz(a, b));
}

#define MFMA_BF16_K32(a, b, c) __builtin_amdgcn_mfma_f32_16x16x32_bf16((a), (b), (c), 0, 0, 0)
#define MFMA_F16_K16(a, b, c)  __builtin_amdgcn_mfma_f32_16x16x16f16((a), (b), (c), 0, 0, 0)

// async global->LDS copy: per-lane global addr, wave-uniform LDS base,
// HW deposits at base + lane*16.
typedef __attribute__((address_space(3))) unsigned int        lds_u32;
typedef const __attribute__((address_space(1))) unsigned int  glob_u32;
__device__ __attribute__((always_inline)) inline void gl_lds16(const void* g, void* l) {
    __builtin_amdgcn_global_load_lds((glob_u32*)g, (lds_u32*)l, 16, 0, 0);
}

// ---------------------------------------------------------------------------
// Kernel 0: C^T B-operand fragments per head (tiny, one-time).
// ---------------------------------------------------------------------------
__global__ __launch_bounds__(256, 1)
void holo_cfrag(const float* __restrict__ Cp, unsigned short* __restrict__ cfrag_g)
{
    const int t = threadIdx.x, lane = t & 63, eb = t >> 6;
    const int l15 = lane & 15, quad = lane >> 4;
    const int h = blockIdx.x;
    const float* Cg = Cp + (size_t)h * Dc * Dc;
    #pragma unroll
    for (int half = 0; half < 2; ++half) {
        short8 b;
        #pragma unroll
        for (int jj = 0; jj < 8; ++jj) {
            const int d = half * 32 + quad * 8 + jj;
            b[jj] = (short)f2bf(Cg[d * Dc + eb * 16 + l15]);
        }
        *(short8*)(&cfrag_g[(((size_t)h * 4 + eb) * 2 + half) * 512 + lane * 8]) = b;
    }
}

// ---------------------------------------------------------------------------
// Kernel 1: prepass, one block per (bh, 64-row tile st). LDS-staged.
// K/V fragment tiles PLANE-SPLIT within each 8KB tile:
//   ktile[0..2047]    = kf0 chunks, (tn*64+lane)*8 u16   (16B per lane)
//   ktile[2048..4095] = kf1 chunks
//   vtile likewise (v0 plane | v1 plane, f16)
// ---------------------------------------------------------------------------
__global__ __launch_bounds__(256, 4)
void holo_prep8(const float* __restrict__ Qp, const float* __restrict__ Kp,
                const float* __restrict__ Vp,
                const unsigned short* __restrict__ cfrag_g,
                unsigned short* __restrict__ qfrag_g,
                unsigned short* __restrict__ kfrag_g,
                _Float16* __restrict__ vfrag_g)
{
    __shared__ unsigned short kt[64 * 72];   // K tile bf16 natural [s][d]
    __shared__ unsigned short qt[64 * 72];   // Q tile bf16 natural [r][d]
    __shared__ _Float16      vt[64 * 72];    // V tile f16 natural [s][d]
    __shared__ unsigned short pf[64 * 72];   // Qrot C->B-frag round trip

    const int t = threadIdx.x, lane = t & 63, w = t >> 6;
    const int l15 = lane & 15, quad = lane >> 4, wb = w * 16;
    const int n = blockIdx.x, bh = n >> 5, st = n & 31, h = bh & 15;
    const int s0 = st * 64;

    const float* Qg = Qp + ((size_t)bh * Tc + s0) * Dc;
    const float* Kg = Kp + ((size_t)bh * Tc + s0) * Dc;
    const float* Vg = Vp + ((size_t)bh * Tc + s0) * Dc;

    // ---- stage all three tiles (coalesced float4 reads, cvt, LDS write) ----
    #pragma unroll
    for (int kk = 0; kk < 4; ++kk) {
        const int flat = kk * 1024 + t * 4;
        const int r = flat >> 6, d0 = flat & 63;
        float4 kv = *(const float4*)(&Kg[flat]);
        ushort4 kp; kp.x = f2bf(kv.x); kp.y = f2bf(kv.y); kp.z = f2bf(kv.z); kp.w = f2bf(kv.w);
        *(ushort4*)(&kt[r * 72 + d0]) = kp;
        float4 qv = *(const float4*)(&Qg[flat]);
        ushort4 qp; qp.x = f2bf(qv.x); qp.y = f2bf(qv.y); qp.z = f2bf(qv.z); qp.w = f2bf(qv.w);
        *(ushort4*)(&qt[r * 72 + d0]) = qp;
        float4 vv = *(const float4*)(&Vg[flat]);
        half4 vp;
        vp[0] = (_Float16)vv.x; vp[1] = (_Float16)vv.y;
        vp[2] = (_Float16)vv.z; vp[3] = (_Float16)vv.w;
        *(half4*)(&vt[r * 72 + d0]) = vp;
    }
    __syncthreads();

    // ---- K fragments (wave w handles tn = w): plane-split writes ----
    {
        const int row = wb + l15;
        ushort8 p0 = *(const ushort8*)(&kt[row * 72 + quad * 8]);
        ushort8 p1 = *(const ushort8*)(&kt[row * 72 + 32 + quad * 8]);
        unsigned short* ktile = kfrag_g + (size_t)(bh * 32 + st) * 4096;
        *(ushort8*)(&ktile[(w * 64 + lane) * 8])        = p0;
        *(ushort8*)(&ktile[2048 + (w * 64 + lane) * 8]) = p1;
    }

    // ---- V fragments: plane-split writes ----
    {
        half8 v0, v1;
        #pragma unroll
        for (int dn = 0; dn < 2; ++dn)
            #pragma unroll
            for (int i = 0; i < 4; ++i)
                v0[dn * 4 + i] = vt[(wb + quad * 4 + i) * 72 + dn * 16 + l15];
        #pragma unroll
        for (int dn = 0; dn < 2; ++dn)
            #pragma unroll
            for (int i = 0; i < 4; ++i)
                v1[dn * 4 + i] = vt[(wb + quad * 4 + i) * 72 + (dn + 2) * 16 + l15];
        _Float16* vtile = vfrag_g + (size_t)(bh * 32 + st) * 4096;
        *(half8*)(&vtile[(w * 64 + lane) * 8])        = v0;
        *(half8*)(&vtile[2048 + (w * 64 + lane) * 8]) = v1;
    }

    // ---- Qrot strip (rows s0+wb..+15): A from qt LDS, B from cfrag ----
    {
        short8 a0 = *(const short8*)(&qt[(wb + l15) * 72 + quad * 8]);
        short8 a1 = *(const short8*)(&qt[(wb + l15) * 72 + 32 + quad * 8]);
        #pragma unroll
        for (int eb = 0; eb < 4; ++eb) {
            short8 b0 = *(const short8*)(&cfrag_g[(((size_t)h * 4 + eb) * 2 + 0) * 512 + lane * 8]);
            short8 b1 = *(const short8*)(&cfrag_g[(((size_t)h * 4 + eb) * 2 + 1) * 512 + lane * 8]);
            f32x4 c = {0.f, 0.f, 0.f, 0.f};
            c = MFMA_BF16_K32(a0, b0, c);
            c = MFMA_BF16_K32(a1, b1, c);
            #pragma unroll
            for (int i = 0; i < 4; ++i)   // fold 0.125 * log2(e)
                pf[(wb + quad * 4 + i) * 72 + eb * 16 + l15] = f2bf(c[i] * 0.18033688f);
        }
        __threadfence_block();   // wave-local rows: order writes before reads
        short8 fa0 = *(const short8*)(&pf[(wb + l15) * 72 + quad * 8]);
        short8 fa1 = *(const short8*)(&pf[(wb + l15) * 72 + 32 + quad * 8]);
        const size_t strip = (size_t)bh * 128 + st * 4 + w;
        *(short8*)(&qfrag_g[strip * 1024 + lane * 8]) = fa0;
        *(short8*)(&qfrag_g[strip * 1024 + 512 + lane * 8]) = fa1;
    }
}

// ---------------------------------------------------------------------------
// Kernel 2: attention. 1 block = 1 (bh,qi) tile, 4 waves = 4 row strips.
// 3-deep LDS ring, counted vmcnt (T4): tile j computed while j+1, j+2 DMAs
// stay in flight across raw s_barriers; drain-0 only in the 2-iter tail.
// Per-tile: entry {vmcnt(8/4/0), barrier}, compute, {barrier, issue j+3}.
// ---------------------------------------------------------------------------
__global__ __launch_bounds__(256, 3)
void holo_attn21(const unsigned short* __restrict__ qfrag_g,
                 const unsigned short* __restrict__ kfrag_g,
                 const _Float16* __restrict__ vfrag_g,
                 float* __restrict__ Op)
{
    __shared__ unsigned short bufK[3][4096];   // 3 x 8KB, plane-split layout
    __shared__ _Float16      bufV[3][4096];    // 3 x 8KB

    const int t = threadIdx.x, lane = t & 63, wid = t >> 6;
    const int l15 = lane & 15, quad = lane >> 4;

    // LPT + XCD-affine mapping: qi descends with dispatch order.
    const int id = blockIdx.x;
    const int xcd = id & 7, sseq = id >> 3;          // 128 blocks per XCD
    const int qi = 31 - (sseq >> 2);
    const int bh = xcd * 4 + (sseq & 3);
    const int q0 = qi * 64;

    const char* kbase = (const char*)(kfrag_g + (size_t)bh * 32 * 4096);
    const char* vbase = (const char*)(vfrag_g + (size_t)bh * 32 * 4096);

    // ---- Qrot B-fragments FIRST, then drain, so loop vmcnt tracks DMA only
    short8 qa0, qa1;
    {
        const size_t strip = (size_t)bh * 128 + qi * 4 + wid;
        qa0 = *(const short8*)(&qfrag_g[strip * 1024 + lane * 8]);
        qa1 = *(const short8*)(&qfrag_g[strip * 1024 + 512 + lane * 8]);
    }
    asm volatile("s_waitcnt vmcnt(0)" ::: "memory");
    __builtin_amdgcn_sched_barrier(0);

    // ---- prologue: issue up to 3 tiles (4 DMAs per wave per tile) ----
    const int npre = (qi + 1 < 3) ? qi + 1 : 3;
    for (int p = 0; p < npre; ++p) {
        const char* ks = kbase + (size_t)p * 8192;
        const char* vs = vbase + (size_t)p * 8192;
        gl_lds16(ks + wid * 1024 + lane * 16,        &bufK[p][wid * 512]);
        gl_lds16(ks + 4096 + wid * 1024 + lane * 16, &bufK[p][2048 + wid * 512]);
        gl_lds16(vs + wid * 1024 + lane * 16,        &bufV[p][wid * 512]);
        gl_lds16(vs + 4096 + wid * 1024 + lane * 16, &bufV[p][2048 + wid * 512]);
    }

    f32x4 o[4];                 // o[dn][i]: O[q=l15][d=dn*16+quad*4+i]
    #pragma unroll
    for (int dn = 0; dn < 4; ++dn) o[dn] = f32x4{0.f, 0.f, 0.f, 0.f};
    float l_lane = 0.f;
    const int rowg = q0 + wid * 16 + l15;   // this lane's global q row

    int fly = npre;   // tiles issued, not yet consumed (block-uniform)
    int cs  = 0;      // ring slot of tile j

    for (int j = 0; j <= qi; ++j) {
        // ---- entry: retire tile j's own-wave DMAs, keep the rest in flight
        if (fly == 3)      { asm volatile("s_waitcnt vmcnt(8)" ::: "memory"); }
        else if (fly == 2) { asm volatile("s_waitcnt vmcnt(4)" ::: "memory"); }
        else               { asm volatile("s_waitcnt vmcnt(0)" ::: "memory"); }
        __builtin_amdgcn_sched_barrier(0);
        __builtin_amdgcn_s_barrier();      // now ALL waves' tile-j DMAs done
        __builtin_amdgcn_sched_barrier(0);

        const unsigned short* Kl = &bufK[cs][0];
        const _Float16*       Vl = &bufV[cs][0];

        // ---- S^T = K * Qrot^T : JIT ds_read_b128 per tn ----
        f32x4 st[4];
        __builtin_amdgcn_s_setprio(1);
        #pragma unroll
        for (int tn = 0; tn < 4; ++tn) {
            short8 k0 = *(const short8*)(&Kl[(tn * 64 + lane) * 8]);
            short8 k1 = *(const short8*)(&Kl[2048 + (tn * 64 + lane) * 8]);
            f32x4 c = {0.f, 0.f, 0.f, 0.f};
            c = MFMA_BF16_K32(k0, qa0, c);
            c = MFMA_BF16_K32(k1, qa1, c);
            st[tn] = c;
        }
        __builtin_amdgcn_s_setprio(0);

        // ---- mask + fixed-shift softmax; packed f16 cvt into B-regs ----
        half4 pa[4];
        #pragma unroll
        for (int tn = 0; tn < 4; ++tn) {
            float p[4];
            #pragma unroll
            for (int i = 0; i < 4; ++i) {
                float sv = st[tn][i];
                if (j == qi) {
                    const int colg = j * 64 + tn * 16 + quad * 4 + i;
                    if (colg > rowg) sv = -1e30f;
                }
                p[i] = __builtin_amdgcn_exp2f(sv);
                l_lane += p[i];
            }
            half2v lo = pkrtz(p[0], p[1]), hi = pkrtz(p[2], p[3]);
            pa[tn] = __builtin_shufflevector(lo, hi, 0, 1, 2, 3);
        }

        // ---- O^T += V^T * P : JIT ds_read_b128 per tn ----
        __builtin_amdgcn_s_setprio(1);
        #pragma unroll
        for (int tn = 0; tn < 4; ++tn) {
            half8 vl = *(const half8*)(&Vl[(tn * 64 + lane) * 8]);
            half8 vh = *(const half8*)(&Vl[2048 + (tn * 64 + lane) * 8]);
            half4 vf0 = __builtin_shufflevector(vl, vl, 0, 1, 2, 3);
            half4 vf1 = __builtin_shufflevector(vl, vl, 4, 5, 6, 7);
            half4 vf2 = __builtin_shufflevector(vh, vh, 0, 1, 2, 3);
            half4 vf3 = __builtin_shufflevector(vh, vh, 4, 5, 6, 7);
            o[0] = MFMA_F16_K16(vf0, pa[tn], o[0]);
            o[1] = MFMA_F16_K16(vf1, pa[tn], o[1]);
            o[2] = MFMA_F16_K16(vf2, pa[tn], o[2]);
            o[3] = MFMA_F16_K16(vf3, pa[tn], o[3]);
        }
        __builtin_amdgcn_s_setprio(0);

        // ---- all waves done reading slot cs -> safe to overwrite ----
        __builtin_amdgcn_sched_barrier(0);
        __builtin_amdgcn_s_barrier();
        __builtin_amdgcn_sched_barrier(0);
        if (j + 3 <= qi) {
            const char* ks = kbase + (size_t)(j + 3) * 8192;
            const char* vs = vbase + (size_t)(j + 3) * 8192;
            gl_lds16(ks + wid * 1024 + lane * 16,        &bufK[cs][wid * 512]);
            gl_lds16(ks + 4096 + wid * 1024 + lane * 16, &bufK[cs][2048 + wid * 512]);
            gl_lds16(vs + wid * 1024 + lane * 16,        &bufV[cs][wid * 512]);
            gl_lds16(vs + 4096 + wid * 1024 + lane * 16, &bufV[cs][2048 + wid * 512]);
        } else {
            --fly;
        }
        cs = (cs == 2) ? 0 : cs + 1;
    }

    // ---- finish l: sum the 4 quad-partials per q=l15 ----
    l_lane += __shfl_xor(l_lane, 16);
    l_lane += __shfl_xor(l_lane, 32);
    const float inv = 1.0f / l_lane;

    // ---- epilogue: coalesced float4 stores (O^T C-layout) ----
    float* dst = Op + ((size_t)bh * Tc + rowg) * Dc;
    #pragma unroll
    for (int dn = 0; dn < 4; ++dn) {
        float4 r;
        r.x = o[dn][0] * inv; r.y = o[dn][1] * inv;
        r.z = o[dn][2] * inv; r.w = o[dn][3] * inv;
        *(float4*)(&dst[dn * 16 + quad * 4]) = r;
    }
}

extern "C" void kernel_launch(void* const* d_in, const int* in_sizes, int n_in,
                              void* d_out, int out_size, void* d_ws, size_t ws_size,
                              hipStream_t stream) {
    const float* Q = (const float*)d_in[0];
    const float* K = (const float*)d_in[1];
    const float* V = (const float*)d_in[2];
    // d_in[3] = causal mask (analytic — unused)
    const float* C = (const float*)d_in[4];
    float* O = (float*)d_out;

    unsigned short* qfrag_w = (unsigned short*)d_ws;              // 8 MiB
    unsigned short* kfrag_w = qfrag_w + REGION;                   // 8 MiB
    _Float16*       vfrag_w = (_Float16*)(kfrag_w + REGION);      // 8 MiB
    unsigned short* cfrag_w = (unsigned short*)(vfrag_w + REGION);// 128 KiB

    holo_cfrag<<<dim3(16), dim3(256), 0, stream>>>(C, cfrag_w);
    holo_prep8<<<dim3(1024), dim3(256), 0, stream>>>(Q, K, V, cfrag_w, qfrag_w, kfrag_w, vfrag_w);
    holo_attn21<<<dim3(1024), dim3(256), 0, stream>>>(qfrag_w, kfrag_w, vfrag_w, O);
}

// Round 13
// 134.842 us; speedup vs baseline: 1.0405x; 1.0099x over previous
//
#include <hip/hip_runtime.h>

// HolonomyAttention: out = softmax_causal((Q @ C_h) K^T / sqrt(D)) V
// B=2 H=16 T=2048 D=64, fp32 in/out.
// Round 22 = r21 kernel set with the cfrag kernel FUSED into prep8:
// each prep block computes its head's C B-fragments inline (64 scalar
// gathers/thread from the 16KB/head C matrix, L2-hot across the 64 blocks
// per head; identical f2bf math). 3 dispatches -> 2, removes cfrag's
// launch slot + 128KB global round trip. attn = r21 verbatim (3-deep
// counted-vmcnt ring, tied-best 136.17).

typedef __attribute__((ext_vector_type(8))) short short8;           // 8 bf16
typedef __attribute__((ext_vector_type(8))) unsigned short ushort8;
typedef __attribute__((ext_vector_type(4))) float f32x4;
typedef __attribute__((ext_vector_type(2))) _Float16 half2v;
typedef __attribute__((ext_vector_type(4))) _Float16 half4;
typedef __attribute__((ext_vector_type(8))) _Float16 half8;

constexpr int Tc = 2048;
constexpr int Dc = 64;
constexpr size_t REGION = (size_t)32 * Tc * Dc;   // 4,194,304 elems = 8 MiB u16

__device__ inline unsigned short f2bf(float f) {   // fp32 -> bf16 RNE
    union { float f; unsigned u; } x; x.f = f;
    return (unsigned short)((x.u + 0x7fffu + ((x.u >> 16) & 1u)) >> 16);
}

__device__ inline half2v pkrtz(float a, float b) {
    return __builtin_bit_cast(half2v, __builtin_amdgcn_cvt_pkrtz(a, b));
}

#define MFMA_BF16_K32(a, b, c) __builtin_amdgcn_mfma_f32_16x16x32_bf16((a), (b), (c), 0, 0, 0)
#define MFMA_F16_K16(a, b, c)  __builtin_amdgcn_mfma_f32_16x16x16f16((a), (b), (c), 0, 0, 0)

// async global->LDS copy: per-lane global addr, wave-uniform LDS base,
// HW deposits at base + lane*16.
typedef __attribute__((address_space(3))) unsigned int        lds_u32;
typedef const __attribute__((address_space(1))) unsigned int  glob_u32;
__device__ __attribute__((always_inline)) inline void gl_lds16(const void* g, void* l) {
    __builtin_amdgcn_global_load_lds((glob_u32*)g, (lds_u32*)l, 16, 0, 0);
}

// ---------------------------------------------------------------------------
// Kernel 1: prepass, one block per (bh, 64-row tile st). LDS-staged.
// C B-fragments computed INLINE (was the cfrag kernel): for its head h,
// each thread gathers b0/b1 short8 per eb directly from C (L2-hot).
// K/V fragment tiles PLANE-SPLIT within each 8KB tile:
//   ktile[0..2047]    = kf0 chunks, (tn*64+lane)*8 u16   (16B per lane)
//   ktile[2048..4095] = kf1 chunks
//   vtile likewise (v0 plane | v1 plane, f16)
// ---------------------------------------------------------------------------
__global__ __launch_bounds__(256, 4)
void holo_prep9(const float* __restrict__ Qp, const float* __restrict__ Kp,
                const float* __restrict__ Vp, const float* __restrict__ Cp,
                unsigned short* __restrict__ qfrag_g,
                unsigned short* __restrict__ kfrag_g,
                _Float16* __restrict__ vfrag_g)
{
    __shared__ unsigned short kt[64 * 72];   // K tile bf16 natural [s][d]
    __shared__ unsigned short qt[64 * 72];   // Q tile bf16 natural [r][d]
    __shared__ _Float16      vt[64 * 72];    // V tile f16 natural [s][d]
    __shared__ unsigned short pf[64 * 72];   // Qrot C->B-frag round trip

    const int t = threadIdx.x, lane = t & 63, w = t >> 6;
    const int l15 = lane & 15, quad = lane >> 4, wb = w * 16;
    const int n = blockIdx.x, bh = n >> 5, st = n & 31, h = bh & 15;
    const int s0 = st * 64;

    const float* Qg = Qp + ((size_t)bh * Tc + s0) * Dc;
    const float* Kg = Kp + ((size_t)bh * Tc + s0) * Dc;
    const float* Vg = Vp + ((size_t)bh * Tc + s0) * Dc;
    const float* Cg = Cp + (size_t)h * Dc * Dc;

    // ---- stage all three tiles (coalesced float4 reads, cvt, LDS write) ----
    #pragma unroll
    for (int kk = 0; kk < 4; ++kk) {
        const int flat = kk * 1024 + t * 4;
        const int r = flat >> 6, d0 = flat & 63;
        float4 kv = *(const float4*)(&Kg[flat]);
        ushort4 kp; kp.x = f2bf(kv.x); kp.y = f2bf(kv.y); kp.z = f2bf(kv.z); kp.w = f2bf(kv.w);
        *(ushort4*)(&kt[r * 72 + d0]) = kp;
        float4 qv = *(const float4*)(&Qg[flat]);
        ushort4 qp; qp.x = f2bf(qv.x); qp.y = f2bf(qv.y); qp.z = f2bf(qv.z); qp.w = f2bf(qv.w);
        *(ushort4*)(&qt[r * 72 + d0]) = qp;
        float4 vv = *(const float4*)(&Vg[flat]);
        half4 vp;
        vp[0] = (_Float16)vv.x; vp[1] = (_Float16)vv.y;
        vp[2] = (_Float16)vv.z; vp[3] = (_Float16)vv.w;
        *(half4*)(&vt[r * 72 + d0]) = vp;
    }
    __syncthreads();

    // ---- K fragments (wave w handles tn = w): plane-split writes ----
    {
        const int row = wb + l15;
        ushort8 p0 = *(const ushort8*)(&kt[row * 72 + quad * 8]);
        ushort8 p1 = *(const ushort8*)(&kt[row * 72 + 32 + quad * 8]);
        unsigned short* ktile = kfrag_g + (size_t)(bh * 32 + st) * 4096;
        *(ushort8*)(&ktile[(w * 64 + lane) * 8])        = p0;
        *(ushort8*)(&ktile[2048 + (w * 64 + lane) * 8]) = p1;
    }

    // ---- V fragments: plane-split writes ----
    {
        half8 v0, v1;
        #pragma unroll
        for (int dn = 0; dn < 2; ++dn)
            #pragma unroll
            for (int i = 0; i < 4; ++i)
                v0[dn * 4 + i] = vt[(wb + quad * 4 + i) * 72 + dn * 16 + l15];
        #pragma unroll
        for (int dn = 0; dn < 2; ++dn)
            #pragma unroll
            for (int i = 0; i < 4; ++i)
                v1[dn * 4 + i] = vt[(wb + quad * 4 + i) * 72 + (dn + 2) * 16 + l15];
        _Float16* vtile = vfrag_g + (size_t)(bh * 32 + st) * 4096;
        *(half8*)(&vtile[(w * 64 + lane) * 8])        = v0;
        *(half8*)(&vtile[2048 + (w * 64 + lane) * 8]) = v1;
    }

    // ---- Qrot strip (rows s0+wb..+15): A from qt LDS, B from C inline ----
    {
        short8 a0 = *(const short8*)(&qt[(wb + l15) * 72 + quad * 8]);
        short8 a1 = *(const short8*)(&qt[(wb + l15) * 72 + 32 + quad * 8]);
        #pragma unroll
        for (int eb = 0; eb < 4; ++eb) {
            // inline C B-fragments (was cfrag kernel; identical mapping:
            // b[jj] = C[(half*32 + quad*8 + jj)*Dc + eb*16 + l15])
            short8 b0, b1;
            #pragma unroll
            for (int jj = 0; jj < 8; ++jj) {
                b0[jj] = (short)f2bf(Cg[(quad * 8 + jj) * Dc + eb * 16 + l15]);
                b1[jj] = (short)f2bf(Cg[(32 + quad * 8 + jj) * Dc + eb * 16 + l15]);
            }
            f32x4 c = {0.f, 0.f, 0.f, 0.f};
            c = MFMA_BF16_K32(a0, b0, c);
            c = MFMA_BF16_K32(a1, b1, c);
            #pragma unroll
            for (int i = 0; i < 4; ++i)   // fold 0.125 * log2(e)
                pf[(wb + quad * 4 + i) * 72 + eb * 16 + l15] = f2bf(c[i] * 0.18033688f);
        }
        __threadfence_block();   // wave-local rows: order writes before reads
        short8 fa0 = *(const short8*)(&pf[(wb + l15) * 72 + quad * 8]);
        short8 fa1 = *(const short8*)(&pf[(wb + l15) * 72 + 32 + quad * 8]);
        const size_t strip = (size_t)bh * 128 + st * 4 + w;
        *(short8*)(&qfrag_g[strip * 1024 + lane * 8]) = fa0;
        *(short8*)(&qfrag_g[strip * 1024 + 512 + lane * 8]) = fa1;
    }
}

// ---------------------------------------------------------------------------
// Kernel 2: attention (r21 verbatim). 1 block = 1 (bh,qi) tile, 4 waves =
// 4 row strips. 3-deep LDS ring, counted vmcnt: tile j computed while
// j+1, j+2 DMAs stay in flight across raw s_barriers; drain-0 only in the
// 2-iter tail. Per-tile: {vmcnt(8/4/0), barrier}, compute, {barrier, issue}.
// ---------------------------------------------------------------------------
__global__ __launch_bounds__(256, 3)
void holo_attn22(const unsigned short* __restrict__ qfrag_g,
                 const unsigned short* __restrict__ kfrag_g,
                 const _Float16* __restrict__ vfrag_g,
                 float* __restrict__ Op)
{
    __shared__ unsigned short bufK[3][4096];   // 3 x 8KB, plane-split layout
    __shared__ _Float16      bufV[3][4096];    // 3 x 8KB

    const int t = threadIdx.x, lane = t & 63, wid = t >> 6;
    const int l15 = lane & 15, quad = lane >> 4;

    // LPT + XCD-affine mapping: qi descends with dispatch order.
    const int id = blockIdx.x;
    const int xcd = id & 7, sseq = id >> 3;          // 128 blocks per XCD
    const int qi = 31 - (sseq >> 2);
    const int bh = xcd * 4 + (sseq & 3);
    const int q0 = qi * 64;

    const char* kbase = (const char*)(kfrag_g + (size_t)bh * 32 * 4096);
    const char* vbase = (const char*)(vfrag_g + (size_t)bh * 32 * 4096);

    // ---- Qrot B-fragments FIRST, then drain, so loop vmcnt tracks DMA only
    short8 qa0, qa1;
    {
        const size_t strip = (size_t)bh * 128 + qi * 4 + wid;
        qa0 = *(const short8*)(&qfrag_g[strip * 1024 + lane * 8]);
        qa1 = *(const short8*)(&qfrag_g[strip * 1024 + 512 + lane * 8]);
    }
    asm volatile("s_waitcnt vmcnt(0)" ::: "memory");
    __builtin_amdgcn_sched_barrier(0);

    // ---- prologue: issue up to 3 tiles (4 DMAs per wave per tile) ----
    const int npre = (qi + 1 < 3) ? qi + 1 : 3;
    for (int p = 0; p < npre; ++p) {
        const char* ks = kbase + (size_t)p * 8192;
        const char* vs = vbase + (size_t)p * 8192;
        gl_lds16(ks + wid * 1024 + lane * 16,        &bufK[p][wid * 512]);
        gl_lds16(ks + 4096 + wid * 1024 + lane * 16, &bufK[p][2048 + wid * 512]);
        gl_lds16(vs + wid * 1024 + lane * 16,        &bufV[p][wid * 512]);
        gl_lds16(vs + 4096 + wid * 1024 + lane * 16, &bufV[p][2048 + wid * 512]);
    }

    f32x4 o[4];                 // o[dn][i]: O[q=l15][d=dn*16+quad*4+i]
    #pragma unroll
    for (int dn = 0; dn < 4; ++dn) o[dn] = f32x4{0.f, 0.f, 0.f, 0.f};
    float l_lane = 0.f;
    const int rowg = q0 + wid * 16 + l15;   // this lane's global q row

    int fly = npre;   // tiles issued, not yet consumed (block-uniform)
    int cs  = 0;      // ring slot of tile j

    for (int j = 0; j <= qi; ++j) {
        // ---- entry: retire tile j's own-wave DMAs, keep the rest in flight
        if (fly == 3)      { asm volatile("s_waitcnt vmcnt(8)" ::: "memory"); }
        else if (fly == 2) { asm volatile("s_waitcnt vmcnt(4)" ::: "memory"); }
        else               { asm volatile("s_waitcnt vmcnt(0)" ::: "memory"); }
        __builtin_amdgcn_sched_barrier(0);
        __builtin_amdgcn_s_barrier();      // now ALL waves' tile-j DMAs done
        __builtin_amdgcn_sched_barrier(0);

        const unsigned short* Kl = &bufK[cs][0];
        const _Float16*       Vl = &bufV[cs][0];

        // ---- S^T = K * Qrot^T : JIT ds_read_b128 per tn ----
        f32x4 st[4];
        __builtin_amdgcn_s_setprio(1);
        #pragma unroll
        for (int tn = 0; tn < 4; ++tn) {
            short8 k0 = *(const short8*)(&Kl[(tn * 64 + lane) * 8]);
            short8 k1 = *(const short8*)(&Kl[2048 + (tn * 64 + lane) * 8]);
            f32x4 c = {0.f, 0.f, 0.f, 0.f};
            c = MFMA_BF16_K32(k0, qa0, c);
            c = MFMA_BF16_K32(k1, qa1, c);
            st[tn] = c;
        }
        __builtin_amdgcn_s_setprio(0);

        // ---- mask + fixed-shift softmax; packed f16 cvt into B-regs ----
        half4 pa[4];
        #pragma unroll
        for (int tn = 0; tn < 4; ++tn) {
            float p[4];
            #pragma unroll
            for (int i = 0; i < 4; ++i) {
                float sv = st[tn][i];
                if (j == qi) {
                    const int colg = j * 64 + tn * 16 + quad * 4 + i;
                    if (colg > rowg) sv = -1e30f;
                }
                p[i] = __builtin_amdgcn_exp2f(sv);
                l_lane += p[i];
            }
            half2v lo = pkrtz(p[0], p[1]), hi = pkrtz(p[2], p[3]);
            pa[tn] = __builtin_shufflevector(lo, hi, 0, 1, 2, 3);
        }

        // ---- O^T += V^T * P : JIT ds_read_b128 per tn ----
        __builtin_amdgcn_s_setprio(1);
        #pragma unroll
        for (int tn = 0; tn < 4; ++tn) {
            half8 vl = *(const half8*)(&Vl[(tn * 64 + lane) * 8]);
            half8 vh = *(const half8*)(&Vl[2048 + (tn * 64 + lane) * 8]);
            half4 vf0 = __builtin_shufflevector(vl, vl, 0, 1, 2, 3);
            half4 vf1 = __builtin_shufflevector(vl, vl, 4, 5, 6, 7);
            half4 vf2 = __builtin_shufflevector(vh, vh, 0, 1, 2, 3);
            half4 vf3 = __builtin_shufflevector(vh, vh, 4, 5, 6, 7);
            o[0] = MFMA_F16_K16(vf0, pa[tn], o[0]);
            o[1] = MFMA_F16_K16(vf1, pa[tn], o[1]);
            o[2] = MFMA_F16_K16(vf2, pa[tn], o[2]);
            o[3] = MFMA_F16_K16(vf3, pa[tn], o[3]);
        }
        __builtin_amdgcn_s_setprio(0);

        // ---- all waves done reading slot cs -> safe to overwrite ----
        __builtin_amdgcn_sched_barrier(0);
        __builtin_amdgcn_s_barrier();
        __builtin_amdgcn_sched_barrier(0);
        if (j + 3 <= qi) {
            const char* ks = kbase + (size_t)(j + 3) * 8192;
            const char* vs = vbase + (size_t)(j + 3) * 8192;
            gl_lds16(ks + wid * 1024 + lane * 16,        &bufK[cs][wid * 512]);
            gl_lds16(ks + 4096 + wid * 1024 + lane * 16, &bufK[cs][2048 + wid * 512]);
            gl_lds16(vs + wid * 1024 + lane * 16,        &bufV[cs][wid * 512]);
            gl_lds16(vs + 4096 + wid * 1024 + lane * 16, &bufV[cs][2048 + wid * 512]);
        } else {
            --fly;
        }
        cs = (cs == 2) ? 0 : cs + 1;
    }

    // ---- finish l: sum the 4 quad-partials per q=l15 ----
    l_lane += __shfl_xor(l_lane, 16);
    l_lane += __shfl_xor(l_lane, 32);
    const float inv = 1.0f / l_lane;

    // ---- epilogue: coalesced float4 stores (O^T C-layout) ----
    float* dst = Op + ((size_t)bh * Tc + rowg) * Dc;
    #pragma unroll
    for (int dn = 0; dn < 4; ++dn) {
        float4 r;
        r.x = o[dn][0] * inv; r.y = o[dn][1] * inv;
        r.z = o[dn][2] * inv; r.w = o[dn][3] * inv;
        *(float4*)(&dst[dn * 16 + quad * 4]) = r;
    }
}

extern "C" void kernel_launch(void* const* d_in, const int* in_sizes, int n_in,
                              void* d_out, int out_size, void* d_ws, size_t ws_size,
                              hipStream_t stream) {
    const float* Q = (const float*)d_in[0];
    const float* K = (const float*)d_in[1];
    const float* V = (const float*)d_in[2];
    // d_in[3] = causal mask (analytic — unused)
    const float* C = (const float*)d_in[4];
    float* O = (float*)d_out;

    unsigned short* qfrag_w = (unsigned short*)d_ws;              // 8 MiB
    unsigned short* kfrag_w = qfrag_w + REGION;                   // 8 MiB
    _Float16*       vfrag_w = (_Float16*)(kfrag_w + REGION);      // 8 MiB

    holo_prep9<<<dim3(1024), dim3(256), 0, stream>>>(Q, K, V, C, qfrag_w, kfrag_w, vfrag_w);
    holo_attn22<<<dim3(1024), dim3(256), 0, stream>>>(qfrag_w, kfrag_w, vfrag_w, O);
}